// Round 2
// baseline (162.742 us; speedup 1.0000x reference)
//
#include <hip/hip_runtime.h>

#define IMG_H 512
#define IMG_W 512
#define BATCH 32
#define TW 256          // tile width (one thread per column)
#define TH 16           // output rows per block
#define NROWS (TH + 6)  // input rows streamed per tile (22)
#define NBLOCKS ((IMG_W / TW) * (IMG_H / TH) * BATCH)  // 2*32*32 = 2048

__global__ __launch_bounds__(256) void ssim_fused(
    const float* __restrict__ X, const float* __restrict__ Y,
    const float* __restrict__ K, double* __restrict__ acc_ws,
    unsigned int* __restrict__ counter, float* __restrict__ out) {
  __shared__ float xr[2][264];
  __shared__ float yr[2][264];
  __shared__ float warp_sums[4];

  const int t = threadIdx.x;
  const int x0 = blockIdx.x * TW;
  const int y0 = blockIdx.y * TH;
  const float* Xb = X + (size_t)blockIdx.z * (IMG_H * IMG_W);
  const float* Yb = Y + (size_t)blockIdx.z * (IMG_H * IMG_W);

  // Exact separable 1D weights from center row of the provided 7x7:
  // k[3][j] = w3*w_j, sum_j w_j = 1  =>  w_j = k[3][j] / sum_j k[3][j].
  float w[7];
  {
    float rs = 0.0f;
#pragma unroll
    for (int j = 0; j < 7; ++j) { w[j] = K[3 * 7 + j]; rs += w[j]; }
    float inv = 1.0f / rs;
#pragma unroll
    for (int j = 0; j < 7; ++j) w[j] *= inv;
  }

  // loop-invariant horizontal bounds
  const int g1 = x0 - 3 + t;
  const bool ok1 = (unsigned)g1 < (unsigned)IMG_W;
  const int g2 = g1 + TW;
  const bool ok2 = (t < 6) && ((unsigned)g2 < (unsigned)IMG_W);

  // 7-slot ring of 5-channel vertical accumulators (indices constant-fold
  // because the row loop is fully unrolled).
  float acc[7][5];
#pragma unroll
  for (int s = 0; s < 7; ++s)
#pragma unroll
    for (int c = 0; c < 5; ++c) acc[s][c] = 0.0f;

  float tsum = 0.0f;

  float pxa, pya, pxb, pyb;
  auto load_row = [&](int r) {
    const int gy = y0 - 3 + r;
    pxa = 0.0f; pya = 0.0f; pxb = 0.0f; pyb = 0.0f;
    if (gy >= 0 && gy < IMG_H) {   // wave-uniform branch
      const float* xrow = Xb + (size_t)gy * IMG_W;
      const float* yrow = Yb + (size_t)gy * IMG_W;
      if (ok1) { pxa = xrow[g1]; pya = yrow[g1]; }
      if (ok2) { pxb = xrow[g2]; pyb = yrow[g2]; }
    }
  };

  load_row(0);

#pragma unroll
  for (int r = 0; r < NROWS; ++r) {   // fully unrolled: r is compile-time
    const int buf = r & 1;

    xr[buf][t] = pxa;
    yr[buf][t] = pya;
    if (t < 6) { xr[buf][t + TW] = pxb; yr[buf][t + TW] = pyb; }

    if (r + 1 < NROWS) load_row(r + 1);

    __syncthreads();

    // horizontal 7-tap, 5 channels
    float hx = 0.0f, hy = 0.0f, hxx = 0.0f, hyy = 0.0f, hxy = 0.0f;
#pragma unroll
    for (int k = 0; k < 7; ++k) {
      const float xv = xr[buf][t + k];
      const float yv = yr[buf][t + k];
      const float wx = w[k] * xv;
      const float wy = w[k] * yv;
      hx  = fmaf(w[k], xv, hx);
      hy  = fmaf(w[k], yv, hy);
      hxx = fmaf(wx, xv, hxx);
      hyy = fmaf(wy, yv, hyy);
      hxy = fmaf(wx, yv, hxy);
    }

    // vertical scatter into the ring; guards fold at compile time
#pragma unroll
    for (int tt = 0; tt < 7; ++tt) {
      const int o = r - tt;
      if (o >= 0 && o < TH) {
        const int slot = o % 7;
        const float wt = w[tt];
        acc[slot][0] = fmaf(wt, hx,  acc[slot][0]);
        acc[slot][1] = fmaf(wt, hy,  acc[slot][1]);
        acc[slot][2] = fmaf(wt, hxx, acc[slot][2]);
        acc[slot][3] = fmaf(wt, hyy, acc[slot][3]);
        acc[slot][4] = fmaf(wt, hxy, acc[slot][4]);
      }
    }

    // output row r-6 complete
    if (r >= 6) {
      const int slot = (r - 6) % 7;
      const float mu_x = acc[slot][0];
      const float mu_y = acc[slot][1];
      const float C1 = 0.0001f, C2 = 0.0009f;
      const float mx2 = mu_x * mu_x;
      const float my2 = mu_y * mu_y;
      const float mxy = mu_x * mu_y;
      const float sxx = acc[slot][2] - mx2;
      const float syy = acc[slot][3] - my2;
      const float sxy = acc[slot][4] - mxy;
      const float num = (2.0f * mxy + C1) * (2.0f * sxy + C2);
      const float den = (mx2 + my2 + C1) * (sxx + syy + C2);
      tsum += num * __builtin_amdgcn_rcpf(den);
#pragma unroll
      for (int c = 0; c < 5; ++c) acc[slot][c] = 0.0f;
    }
  }

  // block reduction: wave64 shuffle -> LDS -> one atomic per block
#pragma unroll
  for (int off = 32; off > 0; off >>= 1) tsum += __shfl_down(tsum, off);
  if ((t & 63) == 0) warp_sums[t >> 6] = tsum;
  __syncthreads();

  if (t == 0) {
    const float bsum = warp_sums[0] + warp_sums[1] + warp_sums[2] + warp_sums[3];
    atomicAdd(acc_ws, (double)bsum);          // device-scope, L3-coherent
    __threadfence();                          // order acc add before counter
    const unsigned int old = atomicAdd(counter, 1u);
    if (old == NBLOCKS - 1) {
      // last block: all partials are in; RMW read gives the coherent value
      const double total = atomicAdd(acc_ws, 0.0);
      out[0] = (float)(total * (1.0 / (double)((size_t)BATCH * IMG_H * IMG_W)));
    }
  }
}

extern "C" void kernel_launch(void* const* d_in, const int* in_sizes, int n_in,
                              void* d_out, int out_size, void* d_ws, size_t ws_size,
                              hipStream_t stream) {
  const float* X = (const float*)d_in[0];
  const float* Y = (const float*)d_in[1];
  const float* K = (const float*)d_in[2];
  float* out = (float*)d_out;
  double* acc = (double*)d_ws;                         // 8 bytes
  unsigned int* counter = (unsigned int*)((char*)d_ws + 8);  // 4 bytes

  hipMemsetAsync(d_ws, 0, 16, stream);  // acc = 0.0, counter = 0
  dim3 grid(IMG_W / TW, IMG_H / TH, BATCH);  // (2, 32, 32) = 2048 blocks
  hipLaunchKernelGGL(ssim_fused, grid, dim3(256), 0, stream, X, Y, K, acc,
                     counter, out);
}